// Round 1
// baseline (516.081 us; speedup 1.0000x reference)
//
#include <hip/hip_runtime.h>
#include <hip/hip_bf16.h>
#include <stdint.h>

typedef __bf16 bf16;
typedef __bf16 bf16x8 __attribute__((ext_vector_type(8)));
typedef float f32x4 __attribute__((ext_vector_type(4)));

#define MFMA_BF16(a, b, c) __builtin_amdgcn_mfma_f32_16x16x32_bf16((a), (b), (c), 0, 0, 0)

// ---------------------------------------------------------------------------
// helpers
// ---------------------------------------------------------------------------
__device__ __forceinline__ void load16f(const float* p, float* r) {
#pragma unroll
  for (int i = 0; i < 4; ++i) {
    float4 v = *(const float4*)(p + 4 * i);
    r[4 * i + 0] = v.x; r[4 * i + 1] = v.y; r[4 * i + 2] = v.z; r[4 * i + 3] = v.w;
  }
}

__device__ __forceinline__ void store16_bf16(bf16* dst, const float* r) {
  bf16x8 v0, v1;
#pragma unroll
  for (int i = 0; i < 8; ++i) { v0[i] = (bf16)r[i]; v1[i] = (bf16)r[8 + i]; }
  *(bf16x8*)(dst) = v0;
  *(bf16x8*)(dst + 8) = v1;
}

// ---------------------------------------------------------------------------
// Kernel 1: qkv = x @ qkv_w.T + qkv_b  (A fp32 -> bf16 in staging)
// M=131072, N=768, K=256.  Output split into Q/K/V, layout [head][token][32] bf16.
// ---------------------------------------------------------------------------
__global__ __launch_bounds__(256, 2)
void qkv_gemm(const float* __restrict__ X, const float* __restrict__ W,
              const float* __restrict__ bias,
              bf16* __restrict__ Qb, bf16* __restrict__ Kb, bf16* __restrict__ Vb)
{
  constexpr int K = 256;
  constexpr int LD = 40;           // padded row: 40 bf16 = 80 B (16B aligned, 2-way banks)
  __shared__ bf16 As[128 * LD];
  __shared__ bf16 Bs[128 * LD];

  const int tid = threadIdx.x;
  const int lane = tid & 63, wave = tid >> 6;
  const int bn = blockIdx.x % 6, bm = blockIdx.x / 6;
  const int m0 = bm * 128, n0 = bn * 128;
  const int sr = tid >> 1, sc = (tid & 1) * 16;       // staging: row, col(elem)
  const int wr = (wave >> 1) * 64, wc = (wave & 1) * 64;
  const int g = lane >> 4, li = lane & 15;

  const f32x4 fzero = {0.f, 0.f, 0.f, 0.f};
  f32x4 acc[4][4];
#pragma unroll
  for (int i = 0; i < 4; ++i)
#pragma unroll
    for (int j = 0; j < 4; ++j) acc[i][j] = fzero;

  const float* Ap = X + (size_t)(m0 + sr) * K + sc;
  const float* Bp = W + (size_t)(n0 + sr) * K + sc;
  float aR[16], bR[16];
  load16f(Ap, aR); load16f(Bp, bR);

#pragma unroll 1
  for (int kt = 0; kt < 8; ++kt) {
    store16_bf16(&As[sr * LD + sc], aR);
    store16_bf16(&Bs[sr * LD + sc], bR);
    __syncthreads();
    if (kt < 7) { Ap += 32; Bp += 32; load16f(Ap, aR); load16f(Bp, bR); }
    bf16x8 af[4], bfr[4];
#pragma unroll
    for (int t = 0; t < 4; ++t) {
      af[t]  = *(const bf16x8*)&As[(wr + t * 16 + li) * LD + g * 8];
      bfr[t] = *(const bf16x8*)&Bs[(wc + t * 16 + li) * LD + g * 8];
    }
#pragma unroll
    for (int i = 0; i < 4; ++i)
#pragma unroll
      for (int j = 0; j < 4; ++j)
        acc[i][j] = MFMA_BF16(af[i], bfr[j], acc[i][j]);
    __syncthreads();
  }

  // epilogue: C row = m0+wr+i*16+g*4+r, col = n0+wc+j*16+li; split q/k/v
#pragma unroll
  for (int i = 0; i < 4; ++i) {
    const int row = m0 + wr + i * 16 + g * 4;
#pragma unroll
    for (int j = 0; j < 4; ++j) {
      const int col = n0 + wc + j * 16 + li;
      const float bv = bias[col];
      const int which = col >> 8;                 // 0=q 1=k 2=v
      bf16* dst = which == 0 ? Qb : (which == 1 ? Kb : Vb);
      const size_t base = (size_t)((col >> 5) & 7) * (131072u * 32u) + (size_t)(col & 31);
#pragma unroll
      for (int r = 0; r < 4; ++r)
        dst[base + (size_t)(row + r) * 32u] = (bf16)(acc[i][j][r] + bv);
    }
  }
}

// ---------------------------------------------------------------------------
// Kernel 2: window attention. One block = (window, head). 4 waves, 256 thr.
//   Q: 64x32  K,V: 256x32 (16x16 halo, zero-padded OOB)
//   S = Q K^T + bias  -> softmax over 256 -> O = P V (den
//   ominator folded into epilogue).
// ---------------------------------------------------------------------------
__global__ __launch_bounds__(256, 2)
void win_attn(const bf16* __restrict__ Qb, const bf16* __restrict__ Kb,
              const bf16* __restrict__ Vb, const float* __restrict__ rel_table,
              bf16* __restrict__ Ob)
{
  constexpr int LDK = 40, LDV = 264, LDP = 264;
  __shared__ __align__(16) char smem[56080];
  bf16* Ks   = (bf16*)smem;                 // [256][40]  (dead after S)
  bf16* Qs   = (bf16*)(smem + 20480);       // [64][40]   (dead after S)
  bf16* Ps   = (bf16*)smem;                 // [64][264]  overlaps Ks+Qs
  bf16* Vt   = (bf16*)(smem + 33792);       // [32][264]  V transposed
  float* red    = (float*)(smem + 50688);   // [4][64]
  float* rowmax = (float*)(smem + 51712);   // [64]
  float* rowsum = (float*)(smem + 51968);   // [64]
  float* biasT  = (float*)(smem + 52224);   // [961] this head's rel bias column

  const int tid = threadIdx.x;
  const int lane = tid & 63, wave = tid >> 6;
  const int g = lane >> 4, li = lane & 15;
  const int bid = blockIdx.x;
  const int w = bid & 2047, h = bid >> 11;        // windows inner for L2 halo reuse
  const int b = w >> 8, wi = (w >> 4) & 15, wj = w & 15;
  const size_t hbase = (size_t)h * (131072u * 32u);
  const size_t bbase = (size_t)b << 14;

  for (int i = tid; i < 961; i += 256) biasT[i] = rel_table[i * 8 + h];

  { // stage Q: rows n=0..63 (always in-bounds)
    const int n = tid >> 2, ch = (tid & 3) * 8;
    const int gi = wi * 8 + (n >> 3), gj = wj * 8 + (n & 7);
    const size_t tok = bbase + (size_t)(gi * 128 + gj);
    *(uint4*)&Qs[n * LDK + ch] = *(const uint4*)(Qb + hbase + tok * 32 + ch);
  }
  { // stage K (row-major, padded) and V (transposed), zero-fill OOB
    const int m = tid;
    const int gi = wi * 8 - 4 + (m >> 4), gj = wj * 8 - 4 + (m & 15);
    const bool ok = (gi >= 0) & (gi < 128) & (gj >= 0) & (gj < 128);
    const size_t tok = bbase + (size_t)(gi * 128 + gj);
    uint4 zero4{};
#pragma unroll
    for (int c = 0; c < 4; ++c) {
      uint4 kv = zero4;
      if (ok) kv = *(const uint4*)(Kb + hbase + tok * 32 + c * 8);
      *(uint4*)&Ks[m * LDK + c * 8] = kv;
    }
#pragma unroll
    for (int c = 0; c < 4; ++c) {
      uint4 vv = zero4;
      if (ok) vv = *(const uint4*)(Vb + hbase + tok * 32 + c * 8);
      const bf16* pv = (const bf16*)&vv;
#pragma unroll
      for (int jj = 0; jj < 8; ++jj) Vt[(c * 8 + jj) * LDV + m] = pv[jj];
    }
  }
  __syncthreads();

  // ---- S = Q K^T : wave handles S cols [wave*64, wave*64+64) ----
  const f32x4 fzero = {0.f, 0.f, 0.f, 0.f};
  f32x4 s[4][4];
#pragma unroll
  for (int i = 0; i < 4; ++i)
#pragma unroll
    for (int j = 0; j < 4; ++j) s[i][j] = fzero;

  bf16x8 qa[4], kb[4];
#pragma unroll
  for (int t = 0; t < 4; ++t) {
    qa[t] = *(const bf16x8*)&Qs[(t * 16 + li) * LDK + g * 8];
    kb[t] = *(const bf16x8*)&Ks[(wave * 64 + t * 16 + li) * LDK + g * 8];
  }
#pragma unroll
  for (int i = 0; i < 4; ++i)
#pragma unroll
    for (int j = 0; j < 4; ++j)
      s[i][j] = MFMA_BF16(qa[i], kb[j], s[i][j]);

  // ---- scale + relative-position bias ----
  const float scale = 0.17677669529663687f;   // 1/sqrt(32)
#pragma unroll
  for (int i = 0; i < 4; ++i)
#pragma unroll
    for (int j = 0; j < 4; ++j) {
      const int m = wave * 64 + j * 16 + li;
      const int ki = m >> 4, kj = m & 15;
#pragma unroll
      for (int r = 0; r < 4; ++r) {
        const int n = i * 16 + g * 4 + r;
        const int bi = ((n >> 3) + 19 - ki) * 31 + ((n & 7) + 19 - kj);
        s[i][j][r] = s[i][j][r] * scale + biasT[bi];
      }
    }

  // ---- row max: 4 local cols -> 16-lane shfl -> cross-wave via LDS ----
  float rmax[4][4];
#pragma unroll
  for (int i = 0; i < 4; ++i)
#pragma unroll
    for (int r = 0; r < 4; ++r) {
      float v = fmaxf(fmaxf(s[i][0][r], s[i][1][r]), fmaxf(s[i][2][r], s[i][3][r]));
#pragma unroll
      for (int off = 1; off < 16; off <<= 1) v = fmaxf(v, __shfl_xor(v, off));
      rmax[i][r] = v;
    }
  if (li == 0) {
#pragma unroll
    for (int i = 0; i < 4; ++i)
#pragma unroll
      for (int r = 0; r < 4; ++r)
        red[wave * 64 + i * 16 + g * 4 + r] = rmax[i][r];
  }
  __syncthreads();
  if (tid < 64)
    rowmax[tid] = fmaxf(fmaxf(red[tid], red[64 + tid]),
                        fmaxf(red[128 + tid], red[192 + tid]));
  __syncthreads();

  // ---- exp, partial sums, write P (bf16) into the dead K/Q region ----
  float rs[4][4];
#pragma unroll
  for (int i = 0; i < 4; ++i)
#pragma unroll
    for (int r = 0; r < 4; ++r) {
      const float mx = rowmax[i * 16 + g * 4 + r];
      float a = 0.f;
#pragma unroll
      for (int j = 0; j < 4; ++j) {
        const float p = __expf(s[i][j][r] - mx);
        s[i][j][r] = p;
        a += p;
      }
#pragma unroll
      for (int off = 1; off < 16; off <<= 1) a += __shfl_xor(a, off);
      rs[i][r] = a;
    }
  if (li == 0) {
#pragma unroll
    for (int i = 0; i < 4; ++i)
#pragma unroll
      for (int r = 0; r < 4; ++r)
        red[wave * 64 + i * 16 + g * 4 + r] = rs[i][r];
  }
#pragma unroll
  for (int i = 0; i < 4; ++i)
#pragma unroll
    for (int j = 0; j < 4; ++j)
#pragma unroll
      for (int r = 0; r < 4; ++r)
        Ps[(i * 16 + g * 4 + r) * LDP + wave * 64 + j * 16 + li] = (bf16)s[i][j][r];
  __syncthreads();
  if (tid < 64)
    rowsum[tid] = red[tid] + red[64 + tid] + red[128 + tid] + red[192 + tid];
  __syncthreads();

  // ---- O = P V : wave handles rows [wave*16, wave*16+16), 2 d-tiles ----
  f32x4 o[2];
  o[0] = fzero; o[1] = fzero;
#pragma unroll
  for (int ks = 0; ks < 8; ++ks) {
    bf16x8 pa = *(const bf16x8*)&Ps[(wave * 16 + li) * LDP + ks * 32 + g * 8];
#pragma unroll
    for (int dj = 0; dj < 2; ++dj) {
      bf16x8 vb = *(const bf16x8*)&Vt[(dj * 16 + li) * LDV + ks * 32 + g * 8];
      o[dj] = MFMA_BF16(pa, vb, o[dj]);
    }
  }
#pragma unroll
  for (int dj = 0; dj < 2; ++dj)
#pragma unroll
    for (int r = 0; r < 4; ++r) {
      const int n = wave * 16 + g * 4 + r;
      const float inv = 1.0f / rowsum[n];
      const int gi = wi * 8 + (n >> 3), gj = wj * 8 + (n & 7);
      const size_t tok = bbase + (size_t)(gi * 128 + gj);
      Ob[tok * 256 + h * 32 + dj * 16 + li] = (bf16)(o[dj][r] * inv);
    }
}

// ---------------------------------------------------------------------------
// Kernel 3: out = attn_out @ proj_w.T + proj_b   (fp32 output to d_out)
// M=131072, N=256, K=256. A bf16, B fp32->bf16 in staging.
// ---------------------------------------------------------------------------
__global__ __launch_bounds__(256, 2)
void proj_gemm(const bf16* __restrict__ A, const float* __restrict__ W,
               const float* __restrict__ bias, float* __restrict__ Out)
{
  constexpr int K = 256;
  constexpr int LD = 40;
  __shared__ bf16 As[128 * LD];
  __shared__ bf16 Bs[128 * LD];

  const int tid = threadIdx.x;
  const int lane = tid & 63, wave = tid >> 6;
  const int bn = blockIdx.x & 1, bm = blockIdx.x >> 1;
  const int m0 = bm * 128, n0 = bn * 128;
  const int sr = tid >> 1, sc = (tid & 1) * 16;
  const int wr = (wave >> 1) * 64, wc = (wave & 1) * 64;
  const int g = lane >> 4, li = lane & 15;

  const f32x4 fzero = {0.f, 0.f, 0.f, 0.f};
  f32x4 acc[4][4];
#pragma unroll
  for (int i = 0; i < 4; ++i)
#pragma unroll
    for (int j = 0; j < 4; ++j) acc[i][j] = fzero;

  const bf16* Ap = A + (size_t)(m0 + sr) * K + sc;
  const float* Bp = W + (size_t)(n0 + sr) * K + sc;
  uint4 aV0, aV1; float bR[16];
  aV0 = *(const uint4*)(Ap); aV1 = *(const uint4*)(Ap + 8);
  load16f(Bp, bR);

#pragma unroll 1
  for (int kt = 0; kt < 8; ++kt) {
    *(uint4*)&As[sr * LD + sc] = aV0;
    *(uint4*)&As[sr * LD + sc + 8] = aV1;
    store16_bf16(&Bs[sr * LD + sc], bR);
    __syncthreads();
    if (kt < 7) {
      Ap += 32; Bp += 32;
      aV0 = *(const uint4*)(Ap); aV1 = *(const uint4*)(Ap + 8);
      load16f(Bp, bR);
    }
    bf16x8 af[4], bfr[4];
#pragma unroll
    for (int t = 0; t < 4; ++t) {
      af[t]  = *(const bf16x8*)&As[(wr + t * 16 + li) * LD + g * 8];
      bfr[t] = *(const bf16x8*)&Bs[(wc + t * 16 + li) * LD + g * 8];
    }
#pragma unroll
    for (int i = 0; i < 4; ++i)
#pragma unroll
      for (int j = 0; j < 4; ++j)
        acc[i][j] = MFMA_BF16(af[i], bfr[j], acc[i][j]);
    __syncthreads();
  }

#pragma unroll
  for (int i = 0; i < 4; ++i) {
    const int row = m0 + wr + i * 16 + g * 4;
#pragma unroll
    for (int j = 0; j < 4; ++j) {
      const int col = n0 + wc + j * 16 + li;
      const float bv = bias[col];
#pragma unroll
      for (int r = 0; r < 4; ++r)
        Out[(size_t)(row + r) * 256 + col] = acc[i][j][r] + bv;
    }
  }
}

// ---------------------------------------------------------------------------
extern "C" void kernel_launch(void* const* d_in, const int* in_sizes, int n_in,
                              void* d_out, int out_size, void* d_ws, size_t ws_size,
                              hipStream_t stream)
{
  const float* x       = (const float*)d_in[0];
  // d_in[1] = mask: unused by the reference
  const float* qkv_w   = (const float*)d_in[2];
  const float* qkv_b   = (const float*)d_in[3];
  const float* proj_w  = (const float*)d_in[4];
  const float* proj_b  = (const float*)d_in[5];
  const float* rel_tab = (const float*)d_in[6];
  float* out = (float*)d_out;

  char* ws = (char*)d_ws;
  bf16* Qb = (bf16*)(ws);                            // [8][131072][32] bf16 = 64 MiB
  bf16* Kb = (bf16*)(ws + (size_t)67108864);         // 64 MiB
  bf16* Vb = (bf16*)(ws + (size_t)134217728);        // 64 MiB
  bf16* Ao = (bf16*)(ws + (size_t)201326592);        // [131072][256] bf16 = 64 MiB

  qkv_gemm<<<dim3(6144), dim3(256), 0, stream>>>(x, qkv_w, qkv_b, Qb, Kb, Vb);
  win_attn<<<dim3(16384), dim3(256), 0, stream>>>(Qb, Kb, Vb, rel_tab, Ao);
  proj_gemm<<<dim3(2048), dim3(256), 0, stream>>>(Ao, proj_w, proj_b, out);
}